// Round 1
// baseline (355.510 us; speedup 1.0000x reference)
//
#include <hip/hip_runtime.h>
#include <math.h>

#define C_DIM 512
#define K_DIM 64
#define N_PIX 784
#define B_DIM 128
#define M_ROWS (B_DIM * N_PIX)   // 100352
#define CC 32                     // C-chunk
#define MT 64                     // rows per block

// exp(20*d - 20) = exp2(KA*d + KB)
#define KA 28.853900817779268f
#define KB (-28.853900817779268f)

// ---------------- Kernel A: normalize anchors (64 blocks x 64 threads) ----------------
__global__ __launch_bounds__(64) void anchors_norm_kernel(const float* __restrict__ a,
                                                          float* __restrict__ an) {
    const int k = blockIdx.x;
    const int l = threadIdx.x;  // 0..63
    const float4* ap = (const float4*)(a + (size_t)k * C_DIM);
    float4 v0 = ap[l];
    float4 v1 = ap[l + 64];
    float ss = v0.x * v0.x + v0.y * v0.y + v0.z * v0.z + v0.w * v0.w +
               v1.x * v1.x + v1.y * v1.y + v1.z * v1.z + v1.w * v1.w;
#pragma unroll
    for (int m = 1; m < 64; m <<= 1) ss += __shfl_xor(ss, m);
    const float rn = 1.0f / (sqrtf(ss) + 1e-12f);
    float4* anp = (float4*)(an + (size_t)k * C_DIM);
    v0.x *= rn; v0.y *= rn; v0.z *= rn; v0.w *= rn;
    v1.x *= rn; v1.y *= rn; v1.z *= rn; v1.w *= rn;
    anp[l] = v0;
    anp[l + 64] = v1;
}

// ---------------- Kernel B: cosine GEMM + T ----------------
// grid = 1568 blocks (64 rows each), 256 threads.
// thread (tm = tid>>4 in [0,16), tk = tid&15) owns rows tm*4..+3, anchors tk*4..+3.
__global__ __launch_bounds__(256) void cost_t_kernel(const float* __restrict__ x,
                                                     const float* __restrict__ an,
                                                     float* __restrict__ Tg) {
    __shared__ float xs[CC][MT + 4];     // transposed: xs[c][row], row-stride 68 floats
    __shared__ float as[CC][K_DIM + 4];  // transposed: as[c][k]
    __shared__ float nrm[MT];

    const int tid = threadIdx.x;
    const int m0 = blockIdx.x * MT;
    const int tk = tid & 15;
    const int tm = tid >> 4;

    const int srow = tid >> 3;  // 0..31 (staging row)
    const int sc4 = tid & 7;    // 0..7  (staging float4 column)
    const int cb = sc4 * 4;

    float acc[4][4] = {};
    float ss0 = 0.f, ss1 = 0.f;

    for (int c0 = 0; c0 < C_DIM; c0 += CC) {
        // global loads (coalesced float4): x rows srow, srow+32; anchors rows srow, srow+32
        const float4 xa = *(const float4*)(x + (size_t)(m0 + srow) * C_DIM + c0 + cb);
        const float4 xb = *(const float4*)(x + (size_t)(m0 + srow + 32) * C_DIM + c0 + cb);
        const float4 aa = *(const float4*)(an + (size_t)srow * C_DIM + c0 + cb);
        const float4 ab = *(const float4*)(an + (size_t)(srow + 32) * C_DIM + c0 + cb);

        ss0 += xa.x * xa.x + xa.y * xa.y + xa.z * xa.z + xa.w * xa.w;
        ss1 += xb.x * xb.x + xb.y * xb.y + xb.z * xb.z + xb.w * xb.w;

        __syncthreads();  // previous iteration's LDS reads done
        xs[cb + 0][srow] = xa.x; xs[cb + 1][srow] = xa.y;
        xs[cb + 2][srow] = xa.z; xs[cb + 3][srow] = xa.w;
        xs[cb + 0][srow + 32] = xb.x; xs[cb + 1][srow + 32] = xb.y;
        xs[cb + 2][srow + 32] = xb.z; xs[cb + 3][srow + 32] = xb.w;
        as[cb + 0][srow] = aa.x; as[cb + 1][srow] = aa.y;
        as[cb + 2][srow] = aa.z; as[cb + 3][srow] = aa.w;
        as[cb + 0][srow + 32] = ab.x; as[cb + 1][srow + 32] = ab.y;
        as[cb + 2][srow + 32] = ab.z; as[cb + 3][srow + 32] = ab.w;
        __syncthreads();

#pragma unroll
        for (int c = 0; c < CC; ++c) {
            const float4 xv = *(const float4*)&xs[c][tm * 4];  // 16B-aligned ds_read_b128
            const float4 av = *(const float4*)&as[c][tk * 4];
            acc[0][0] += xv.x * av.x; acc[0][1] += xv.x * av.y;
            acc[0][2] += xv.x * av.z; acc[0][3] += xv.x * av.w;
            acc[1][0] += xv.y * av.x; acc[1][1] += xv.y * av.y;
            acc[1][2] += xv.y * av.z; acc[1][3] += xv.y * av.w;
            acc[2][0] += xv.z * av.x; acc[2][1] += xv.z * av.y;
            acc[2][2] += xv.z * av.z; acc[2][3] += xv.z * av.w;
            acc[3][0] += xv.w * av.x; acc[3][1] += xv.w * av.y;
            acc[3][2] += xv.w * av.z; acc[3][3] += xv.w * av.w;
        }
    }

    // row sumsq: reduce over the 8 lanes (bits 0..2) sharing a staging row
    ss0 += __shfl_xor(ss0, 1); ss0 += __shfl_xor(ss0, 2); ss0 += __shfl_xor(ss0, 4);
    ss1 += __shfl_xor(ss1, 1); ss1 += __shfl_xor(ss1, 2); ss1 += __shfl_xor(ss1, 4);
    if (sc4 == 0) {
        nrm[srow] = 1.0f / (sqrtf(ss0) + 1e-12f);
        nrm[srow + 32] = 1.0f / (sqrtf(ss1) + 1e-12f);
    }
    __syncthreads();

    float tpart[4];
#pragma unroll
    for (int i = 0; i < 4; ++i) {
        const float rn = nrm[tm * 4 + i];
        float t = 0.f;
#pragma unroll
        for (int j = 0; j < 4; ++j) {
            const float d = acc[i][j] * rn;       // cosine in [-1,1]
            t += exp2f(KA * d + KB);              // exp(20 d - 20) <= 1, no overflow
        }
        tpart[i] = t;
    }
    // reduce over the 16 tk lanes (bits 0..3)
#pragma unroll
    for (int i = 0; i < 4; ++i) {
        float t = tpart[i];
        t += __shfl_xor(t, 1); t += __shfl_xor(t, 2);
        t += __shfl_xor(t, 4); t += __shfl_xor(t, 8);
        tpart[i] = t;
    }
    if (tk == 0) {
#pragma unroll
        for (int i = 0; i < 4; ++i) Tg[m0 + tm * 4 + i] = tpart[i];
    }
}

// ---------------- Kernel C: Sinkhorn scalar recurrence, in-place coef ----------------
// w_{t+1} = w_t * (mu*N) / sum_n (w T)/(1+w T);  coef = (2/N) * wT/(1+wT)
__global__ __launch_bounds__(256) void sinkhorn_kernel(float* __restrict__ Tc) {
    const int b = blockIdx.x;
    const int tid = threadIdx.x;
    __shared__ float wsum[4];
    __shared__ float wsh;
    float r[4];
#pragma unroll
    for (int q = 0; q < 4; ++q) {
        const int n = tid + q * 256;
        r[q] = (n < N_PIX) ? Tc[b * N_PIX + n] : 0.f;  // T=0 contributes 0
    }
    float w = 1.0f;
    for (int it = 0; it < 10; ++it) {
        float p = 0.f;
#pragma unroll
        for (int q = 0; q < 4; ++q) {
            const float wr = w * r[q];
            p += wr / (1.0f + wr);
        }
#pragma unroll
        for (int m = 1; m < 64; m <<= 1) p += __shfl_xor(p, m);
        if ((tid & 63) == 0) wsum[tid >> 6] = p;
        __syncthreads();
        if (tid == 0) {
            const float s = wsum[0] + wsum[1] + wsum[2] + wsum[3];
            wsh = w * 392.0f / s;  // mu*N = 0.5*784
        }
        __syncthreads();
        w = wsh;
    }
    const float scale = 2.0f / 784.0f;
#pragma unroll
    for (int q = 0; q < 4; ++q) {
        const int n = tid + q * 256;
        if (n < N_PIX) {
            const float wr = w * r[q];
            Tc[b * N_PIX + n] = scale * wr / (1.0f + wr);
        }
    }
}

// ---------------- Kernel D: weighted pooling ----------------
// grid = 128 batches x 8 n-chunks; out must be pre-zeroed.
__global__ __launch_bounds__(256) void pool_kernel(const float* __restrict__ x,
                                                   const float* __restrict__ coef,
                                                   float* __restrict__ out) {
    const int bid = blockIdx.x;
    const int b = bid >> 3;
    const int n0 = (bid & 7) * 98;  // 8*98 = 784
    const int c2 = threadIdx.x * 2;
    const float* xb = x + (size_t)b * N_PIX * C_DIM;
    const float* cf = coef + b * N_PIX;
    float2 acc = {0.f, 0.f};
    for (int n = n0; n < n0 + 98; ++n) {
        const float a = cf[n];  // uniform -> scalar load
        const float2 xv = *(const float2*)(xb + (size_t)n * C_DIM + c2);
        acc.x += a * xv.x;
        acc.y += a * xv.y;
    }
    atomicAdd(&out[b * C_DIM + c2], acc.x);
    atomicAdd(&out[b * C_DIM + c2 + 1], acc.y);
}

extern "C" void kernel_launch(void* const* d_in, const int* in_sizes, int n_in,
                              void* d_out, int out_size, void* d_ws, size_t ws_size,
                              hipStream_t stream) {
    const float* x = (const float*)d_in[0];       // (128,28,28,512) fp32
    const float* anchors = (const float*)d_in[1]; // (64,512) fp32
    float* out = (float*)d_out;                   // (128,512) fp32

    float* an = (float*)d_ws;                     // 64*512 floats
    float* Tc = (float*)d_ws + (size_t)K_DIM * C_DIM;  // 128*784 floats (T, then coef in-place)

    anchors_norm_kernel<<<K_DIM, 64, 0, stream>>>(anchors, an);
    cost_t_kernel<<<M_ROWS / MT, 256, 0, stream>>>(x, an, Tc);
    sinkhorn_kernel<<<B_DIM, 256, 0, stream>>>(Tc);
    hipMemsetAsync(d_out, 0, (size_t)out_size * sizeof(float), stream);
    pool_kernel<<<B_DIM * 8, 256, 0, stream>>>(x, Tc, out);
}